// Round 5
// baseline (289.188 us; speedup 1.0000x reference)
//
#include <hip/hip_runtime.h>
#include <hip/hip_bf16.h>
#include <math.h>

#define L 2048
#define D 256

typedef __attribute__((ext_vector_type(8))) short bf16x8;
typedef __attribute__((ext_vector_type(4))) float f32x4;
typedef __attribute__((ext_vector_type(4))) int i32x4;

__device__ __forceinline__ unsigned short f2bf(float f) {
    union { float f; unsigned int u; } v; v.f = f;
    unsigned int r = v.u + 0x7FFFu + ((v.u >> 16) & 1u);   // RNE
    return (unsigned short)(r >> 16);
}

// --- transpose Wv, Wo (f32 k-major) -> bf16 n-major ---------------------
__global__ __launch_bounds__(256) void wtrans_kernel(
    const float* __restrict__ Wv, const float* __restrict__ Wo,
    unsigned short* __restrict__ Wvt, unsigned short* __restrict__ Wot) {
    int idx = blockIdx.x * 256 + threadIdx.x;       // 0..131071
    int which = idx >> 16;
    int e = idx & 65535;
    int n = e >> 8, k = e & 255;
    const float* W = which ? Wo : Wv;
    unsigned short* Wt = which ? Wot : Wvt;
    Wt[n * 256 + k] = f2bf(W[k * 256 + n]);
}

// --- LDS-free GEMM: v = value @ Wv + bv, stored TRANSPOSED bf16 Vt[b][n][j]
__global__ __launch_bounds__(256) void gemm_v_kernel(
    const float* __restrict__ A,
    const unsigned short* __restrict__ Wt,   // [256][256] bf16 n-major
    const float* __restrict__ bias,
    unsigned short* __restrict__ Vt) {
    const int wave = threadIdx.x >> 6;
    const int lane = threadIdx.x & 63;
    const int mh = wave >> 1, nh = wave & 1;
    const int lm = lane & 15, q = lane >> 4;
    const int m0 = blockIdx.x * 64;
    const int n0 = blockIdx.y * 128;

    f32x4 acc[2][4];
#pragma unroll
    for (int i = 0; i < 2; i++)
#pragma unroll
        for (int j = 0; j < 4; j++) acc[i][j] = (f32x4)(0.f);

    int arow[2];
    arow[0] = m0 + mh * 32 + lm;
    arow[1] = arow[0] + 16;
    int ncol[4];
#pragma unroll
    for (int nf = 0; nf < 4; nf++) ncol[nf] = n0 + nh * 64 + nf * 16 + lm;

    for (int k0 = 0; k0 < 256; k0 += 32) {
        int kq = k0 + q * 8;
        bf16x8 bfr[4];
#pragma unroll
        for (int nf = 0; nf < 4; nf++)
            bfr[nf] = *reinterpret_cast<const bf16x8*>(Wt + ncol[nf] * 256 + kq);
        bf16x8 afr[2];
#pragma unroll
        for (int mf = 0; mf < 2; mf++) {
            const float* ap = A + arow[mf] * 256 + kq;
            f32x4 a0 = *reinterpret_cast<const f32x4*>(ap);
            f32x4 a1 = *reinterpret_cast<const f32x4*>(ap + 4);
            bf16x8 t;
#pragma unroll
            for (int e = 0; e < 4; e++) t[e] = (short)f2bf(a0[e]);
#pragma unroll
            for (int e = 0; e < 4; e++) t[4 + e] = (short)f2bf(a1[e]);
            afr[mf] = t;
        }
#pragma unroll
        for (int mf = 0; mf < 2; mf++)
#pragma unroll
            for (int nf = 0; nf < 4; nf++)
                acc[mf][nf] = __builtin_amdgcn_mfma_f32_16x16x32_bf16(
                    afr[mf], bfr[nf], acc[mf][nf], 0, 0, 0);
    }

#pragma unroll
    for (int mf = 0; mf < 2; mf++) {
        int mrow = m0 + mh * 32 + mf * 16 + q * 4;   // rows mrow..mrow+3
#pragma unroll
        for (int nf = 0; nf < 4; nf++) {
            int n = ncol[nf];
            float bias_n = bias[n];
            int b = mrow >> 11;
            int j = mrow & 2047;
            unsigned short* dst = Vt + (size_t)b * (D * L) + (size_t)n * L + j;
            ushort4 pk;
            pk.x = f2bf(acc[mf][nf][0] + bias_n);
            pk.y = f2bf(acc[mf][nf][1] + bias_n);
            pk.z = f2bf(acc[mf][nf][2] + bias_n);
            pk.w = f2bf(acc[mf][nf][3] + bias_n);
            *reinterpret_cast<ushort4*>(dst) = pk;
        }
    }
}

// --- PURE STREAMING with explicit depth-2 register pipeline -------------
// One wave per HALF row (16384 waves). 4 chunks of 256 f32 per wave.
// Next chunk's a/m/p loads issued before current chunk's exp/pack/store:
// >=6 outstanding 1KB loads per wave at all times. No LDS, no barriers.
__global__ __launch_bounds__(256) void p_kernel(
    const float* __restrict__ atten, const float* __restrict__ mask,
    const int* __restrict__ pad, unsigned short* __restrict__ P,
    float* __restrict__ lsum2) {
    const int wid = blockIdx.x * 4 + (threadIdx.x >> 6);   // 0..16383
    const int row = wid >> 1, h = wid & 1;
    const int lane = threadIdx.x & 63;

    const size_t base = (size_t)row * L + h * 1024 + lane * 4;
    const float* at = atten + base;
    const float* mk = mask  + base;
    const int*   pd = pad   + base;
    unsigned short* Pr = P + base;

    f32x4 a0 = *reinterpret_cast<const f32x4*>(at);
    f32x4 m0 = *reinterpret_cast<const f32x4*>(mk);
    i32x4 p0 = *reinterpret_cast<const i32x4*>(pd);

    float l_th = 0.f;
#pragma unroll
    for (int c = 0; c < 4; c++) {
        f32x4 a1, m1; i32x4 p1;
        if (c < 3) {
            const int off = (c + 1) * 256;
            a1 = *reinterpret_cast<const f32x4*>(at + off);
            m1 = *reinterpret_cast<const f32x4*>(mk + off);
            p1 = *reinterpret_cast<const i32x4*>(pd + off);
        }
        ushort4 pk;
        float pv;
        pv = (m0[0] < 0.5f || p0[0] == 0) ? 0.f : __expf(a0[0]); l_th += pv; pk.x = f2bf(pv);
        pv = (m0[1] < 0.5f || p0[1] == 0) ? 0.f : __expf(a0[1]); l_th += pv; pk.y = f2bf(pv);
        pv = (m0[2] < 0.5f || p0[2] == 0) ? 0.f : __expf(a0[2]); l_th += pv; pk.z = f2bf(pv);
        pv = (m0[3] < 0.5f || p0[3] == 0) ? 0.f : __expf(a0[3]); l_th += pv; pk.w = f2bf(pv);
        *reinterpret_cast<ushort4*>(Pr + c * 256) = pk;
        a0 = a1; m0 = m1; p0 = p1;
    }
#pragma unroll
    for (int off = 1; off < 64; off <<= 1) l_th += __shfl_xor(l_th, off);
    if (lane == 0) lsum2[wid] = l_th;
}

// --- split-K GEMM  part[sk] = P[.., sk*512:+512] @ Vt^T ------------------
// grid (256 row-tiles, 4 sk). Block = 32 rows x 256 n, 4 waves (n=64 each).
// Barrier-free, kk-granular register pipeline, direct global frag loads.
__global__ __launch_bounds__(256) void pv_split_kernel(
    const unsigned short* __restrict__ P, const unsigned short* __restrict__ Vt,
    float* __restrict__ part) {
    const int rb = blockIdx.x;          // 0..255
    const int sk = blockIdx.y;          // 0..3
    const int tid = threadIdx.x;
    const int w = tid >> 6, lane = tid & 63;
    const int lm = lane & 15, q = lane >> 4;
    const int b = rb >> 6;
    const int row0 = rb * 32;

    const unsigned short* pA = P + (size_t)row0 * L + sk * 512 + q * 8;
    const unsigned short* pB = Vt + (size_t)b * (D * L) + (size_t)(w * 64) * L
                             + sk * 512 + q * 8;

    f32x4 acc[2][4];
#pragma unroll
    for (int i = 0; i < 2; i++)
#pragma unroll
        for (int j = 0; j < 4; j++) acc[i][j] = (f32x4)(0.f);

    bf16x8 Ac[2], Bc[4], An[2], Bn[4];
#pragma unroll
    for (int mf = 0; mf < 2; mf++)
        Ac[mf] = *reinterpret_cast<const bf16x8*>(pA + (mf * 16 + lm) * L);
#pragma unroll
    for (int nf = 0; nf < 4; nf++)
        Bc[nf] = *reinterpret_cast<const bf16x8*>(pB + (nf * 16 + lm) * L);

    for (int t = 0; t < 16; t++) {
        if (t < 15) {
            const int kn = (t + 1) * 32;
#pragma unroll
            for (int mf = 0; mf < 2; mf++)
                An[mf] = *reinterpret_cast<const bf16x8*>(pA + (mf * 16 + lm) * L + kn);
#pragma unroll
            for (int nf = 0; nf < 4; nf++)
                Bn[nf] = *reinterpret_cast<const bf16x8*>(pB + (nf * 16 + lm) * L + kn);
        }
#pragma unroll
        for (int mf = 0; mf < 2; mf++)
#pragma unroll
            for (int nf = 0; nf < 4; nf++)
                acc[mf][nf] = __builtin_amdgcn_mfma_f32_16x16x32_bf16(
                    Ac[mf], Bc[nf], acc[mf][nf], 0, 0, 0);
#pragma unroll
        for (int mf = 0; mf < 2; mf++) Ac[mf] = An[mf];
#pragma unroll
        for (int nf = 0; nf < 4; nf++) Bc[nf] = Bn[nf];
    }

    // part[sk][rb][32][256]
    float* pb = part + ((size_t)sk * 256 + rb) * (32 * 256);
#pragma unroll
    for (int mf = 0; mf < 2; mf++)
#pragma unroll
        for (int nf = 0; nf < 4; nf++) {
            int col = w * 64 + nf * 16 + lm;
#pragma unroll
            for (int rg = 0; rg < 4; rg++)
                pb[(mf * 16 + q * 4 + rg) * 256 + col] = acc[mf][nf][rg];
        }
}

// --- combine 4 sk-partials, normalize, fused out-GEMM -------------------
// grid 512 blocks x 16 rows each.
__global__ __launch_bounds__(256) void combine_gemm_kernel(
    const float* __restrict__ part, const float* __restrict__ lsum2,
    const unsigned short* __restrict__ Wot, const float* __restrict__ bo,
    float* __restrict__ out) {
    const int cb = blockIdx.x;        // 0..511 -> rows cb*16..+15
    const int tid = threadIdx.x;
    const int w = tid >> 6, lane = tid & 63;
    const int lm = lane & 15, q = lane >> 4;
    const int rb = cb >> 1;
    const int rlo = (cb & 1) * 16;

    __shared__ __align__(16) unsigned short Alds[16][264];

    // load + combine partials: thread t -> row r16 = t>>4, cols (t&15)*16..+15
    {
        const int r16 = tid >> 4;
        const int c0 = (tid & 15) * 16;
        const int g = cb * 16 + r16;
        float l = lsum2[2 * g] + lsum2[2 * g + 1];
        float inv = 1.f / l;
        const float* pb = part + (size_t)rb * (32 * 256) + (rlo + r16) * 256 + c0;
#pragma unroll
        for (int e = 0; e < 16; e += 4) {
            f32x4 s = (f32x4)(0.f);
#pragma unroll
            for (int skp = 0; skp < 4; skp++)
                s += *reinterpret_cast<const f32x4*>(pb + (size_t)skp * (256 * 32 * 256) + e);
            s *= inv;
            ushort4 pk;
            pk.x = f2bf(s[0]); pk.y = f2bf(s[1]); pk.z = f2bf(s[2]); pk.w = f2bf(s[3]);
            *reinterpret_cast<ushort4*>(&Alds[r16][c0 + e]) = pk;
        }
    }
    __syncthreads();

    // out = T @ Wo + bo   (16x256 @ 256x256, A from LDS, B = Wot global/L2)
    f32x4 oacc[4];
#pragma unroll
    for (int j = 0; j < 4; j++) oacc[j] = (f32x4)(0.f);
    int ncol[4];
#pragma unroll
    for (int nf = 0; nf < 4; nf++) ncol[nf] = w * 64 + nf * 16 + lm;

    for (int kk = 0; kk < 8; kk++) {
        int kq = kk * 32 + q * 8;
        bf16x8 bfr[4];
#pragma unroll
        for (int nf = 0; nf < 4; nf++)
            bfr[nf] = *reinterpret_cast<const bf16x8*>(Wot + ncol[nf] * 256 + kq);
        bf16x8 afr = *reinterpret_cast<const bf16x8*>(&Alds[lm][kq]);
#pragma unroll
        for (int nf = 0; nf < 4; nf++)
            oacc[nf] = __builtin_amdgcn_mfma_f32_16x16x32_bf16(
                afr, bfr[nf], oacc[nf], 0, 0, 0);
    }

    const int mrow = cb * 16 + q * 4;
#pragma unroll
    for (int nf = 0; nf < 4; nf++) {
        int n = ncol[nf];
        float bn = bo[n];
#pragma unroll
        for (int rg = 0; rg < 4; rg++)
            out[(size_t)(mrow + rg) * 256 + n] = oacc[nf][rg] + bn;
    }
}

extern "C" void kernel_launch(void* const* d_in, const int* in_sizes, int n_in,
                              void* d_out, int out_size, void* d_ws, size_t ws_size,
                              hipStream_t stream) {
    (void)in_sizes; (void)n_in; (void)out_size; (void)ws_size;
    const float* atten = (const float*)d_in[0];
    const float* value = (const float*)d_in[1];
    const float* mask  = (const float*)d_in[2];
    const int*   pad   = (const int*)d_in[3];
    const float* Wv    = (const float*)d_in[4];
    const float* bv    = (const float*)d_in[5];
    const float* Wo    = (const float*)d_in[6];
    const float* bo    = (const float*)d_in[7];
    float* out = (float*)d_out;

    char* ws = (char*)d_ws;
    unsigned short* Vt  = (unsigned short*)(ws);              // 4 MB  bf16 [B][D][L]
    unsigned short* Wvt = (unsigned short*)(ws + 4194304);    // 128 KB
    unsigned short* Wot = (unsigned short*)(ws + 4325376);    // 128 KB
    unsigned short* P   = (unsigned short*)(ws + 4456448);    // 33.55 MB bf16 [8192][2048]
    float* lsum2        = (float*)(ws + 38010880);            // 64 KB
    float* part         = (float*)(ws + 38076416);            // 33.55 MB f32 [4][256][32][256]

    wtrans_kernel<<<512, 256, 0, stream>>>(Wv, Wo, Wvt, Wot);
    gemm_v_kernel<<<dim3(128, 2), 256, 0, stream>>>(value, Wvt, bv, Vt);
    p_kernel<<<4096, 256, 0, stream>>>(atten, mask, pad, P, lsum2);
    pv_split_kernel<<<dim3(256, 4), 256, 0, stream>>>(P, Vt, part);
    combine_gemm_kernel<<<512, 256, 0, stream>>>(part, lsum2, Wot, bo, out);
}